// Round 1
// baseline (2644.118 us; speedup 1.0000x reference)
//
#include <hip/hip_runtime.h>
#include <hip/hip_bf16.h>

typedef __bf16 bf16_t;
typedef __attribute__((ext_vector_type(8))) __bf16 bf16x8;
typedef __attribute__((ext_vector_type(4))) float f32x4;

#define DIM 128

// ---------------- weight prep: Wc[s][n][k256] bf16, s = layer*2 + type ----------
__global__ void prep_weights(const float* __restrict__ Wl, const float* __restrict__ Wr,
                             bf16_t* __restrict__ Wc) {
    int idx = blockIdx.x * blockDim.x + threadIdx.x;   // over 6*128*256
    if (idx >= 6 * 128 * 256) return;
    int k = idx & 255;
    int n = (idx >> 8) & 127;
    int s = idx >> 15;                                  // 0..5
    float v;
    if (k < 128) v = Wl[((size_t)s * 128 + n) * 128 + k];
    else         v = Wr[((size_t)s * 128 + n) * 128 + (k - 128)];
    Wc[idx] = (bf16_t)v;
}

// ---------------- degree count + inverse ----------------
__global__ void count_edges(const int* __restrict__ dst, int* __restrict__ cnt, int E) {
    int i = blockIdx.x * blockDim.x + threadIdx.x;
    if (i < E) atomicAdd(&cnt[dst[i]], 1);
}

__global__ void make_inv(const int* __restrict__ cnt, float* __restrict__ inv, int n) {
    int i = blockIdx.x * blockDim.x + threadIdx.x;
    if (i < n) inv[i] = 1.0f / (float)max(cnt[i], 1);
}

// ---------------- scatter-mean: one wave per edge, lane = 2 columns -------------
__global__ __launch_bounds__(256) void scatter_mean(
    const float* __restrict__ xsrc, const int* __restrict__ src,
    const int* __restrict__ dst, const float* __restrict__ inv,
    float* __restrict__ agg, int E) {
    int e = blockIdx.x * 4 + (threadIdx.x >> 6);
    if (e >= E) return;
    int lane = threadIdx.x & 63;
    int s = src[e];
    int d = dst[e];
    float w = inv[d];
    const float2* sp = (const float2*)(xsrc + (size_t)s * DIM);
    float2 v = sp[lane];
    float* ap = agg + (size_t)d * DIM + lane * 2;
    unsafeAtomicAdd(ap,     v.x * w);
    unsafeAtomicAdd(ap + 1, v.y * w);
}

// ---------------- fused GEMM: out = A0@Wl.T + bias + A1@Wr.T (+ReLU) ------------
// A0 = agg (already mean-scaled), A1 = x_dst, both [M,128] f32.
// Wc = [128 n][256 k] bf16 (k<128 -> Wl, k>=128 -> Wr).
// MFMA 16x16x32 bf16. Block = 4 waves, each wave 16 rows x 128 cols.
template <bool RELU>
__global__ __launch_bounds__(256) void gemm_fused(
    const float* __restrict__ A0, const float* __restrict__ A1,
    const bf16_t* __restrict__ Wc, const float* __restrict__ bias,
    float* __restrict__ out, int M) {
    int wave = threadIdx.x >> 6;
    int lane = threadIdx.x & 63;
    int quad = lane >> 4;
    int l16  = lane & 15;
    int rowBase = blockIdx.x * 64 + wave * 16;
    int mrow = rowBase + l16;                 // A-operand row for this lane
    if (mrow >= M) mrow = M - 1;              // clamp; stores are guarded

    f32x4 acc[8];
#pragma unroll
    for (int ct = 0; ct < 8; ++ct) acc[ct] = (f32x4){0.f, 0.f, 0.f, 0.f};

#pragma unroll
    for (int kt = 0; kt < 8; ++kt) {
        const float* srcp = (kt < 4)
            ? (A0 + (size_t)mrow * DIM + kt * 32)
            : (A1 + (size_t)mrow * DIM + (kt - 4) * 32);
        const float4* p = (const float4*)(srcp + quad * 8);
        float4 a0 = p[0];
        float4 a1 = p[1];
        bf16x8 af;
        af[0] = (bf16_t)a0.x; af[1] = (bf16_t)a0.y;
        af[2] = (bf16_t)a0.z; af[3] = (bf16_t)a0.w;
        af[4] = (bf16_t)a1.x; af[5] = (bf16_t)a1.y;
        af[6] = (bf16_t)a1.z; af[7] = (bf16_t)a1.w;
#pragma unroll
        for (int ct = 0; ct < 8; ++ct) {
            const bf16x8* bp =
                (const bf16x8*)(Wc + ((size_t)(ct * 16 + l16)) * 256 + kt * 32 + quad * 8);
            bf16x8 bf = *bp;
            acc[ct] = __builtin_amdgcn_mfma_f32_16x16x32_bf16(af, bf, acc[ct], 0, 0, 0);
        }
    }

    // C/D layout: col = lane&15, row = quad*4 + reg   [m89/m91-verified]
#pragma unroll
    for (int ct = 0; ct < 8; ++ct) {
        int col = ct * 16 + l16;
        float b = bias[col];
#pragma unroll
        for (int r = 0; r < 4; ++r) {
            int row = rowBase + quad * 4 + r;
            if (row < M) {
                float v = acc[ct][r] + b;
                if (RELU) v = fmaxf(v, 0.f);
                out[(size_t)row * DIM + col] = v;
            }
        }
    }
}

// ---------------- launch ----------------
extern "C" void kernel_launch(void* const* d_in, const int* in_sizes, int n_in,
                              void* d_out, int out_size, void* d_ws, size_t ws_size,
                              hipStream_t stream) {
    const float* x_m = (const float*)d_in[0];
    const float* x_t = (const float*)d_in[1];
    const float* Wl  = (const float*)d_in[2];
    const float* bl  = (const float*)d_in[3];
    const float* Wr  = (const float*)d_in[4];
    const int* e_mt  = (const int*)d_in[5];
    const int* e_tm  = (const int*)d_in[6];

    const int Mm = in_sizes[0] / DIM;     // 100000 musicians
    const int Mt = in_sizes[1] / DIM;     // 100000 tracks
    const int E  = in_sizes[5] / 2;       // 400000

    float* out_m = (float*)d_out;
    float* out_t = (float*)d_out + (size_t)Mm * DIM;

    char* ws = (char*)d_ws;
    size_t off = 0;
    auto alloc = [&](size_t bytes) -> void* {
        void* p = ws + off;
        off += (bytes + 255) & ~(size_t)255;
        return p;
    };
    float*  xm2   = (float*)alloc((size_t)Mm * DIM * 4);
    float*  xt2   = (float*)alloc((size_t)Mt * DIM * 4);
    float*  agg   = (float*)alloc((size_t)((Mm > Mt) ? Mm : Mt) * DIM * 4);
    float*  inv_t = (float*)alloc((size_t)Mt * 4);
    float*  inv_m = (float*)alloc((size_t)Mm * 4);
    int*    cnt_t = (int*)alloc((size_t)Mt * 4);
    int*    cnt_m = (int*)alloc((size_t)Mm * 4);
    bf16_t* Wc    = (bf16_t*)alloc((size_t)6 * 128 * 256 * 2);

    // one-time (per launch) structure prep
    hipMemsetAsync(cnt_t, 0, (size_t)Mt * 4, stream);
    hipMemsetAsync(cnt_m, 0, (size_t)Mm * 4, stream);
    prep_weights<<<(6 * 128 * 256 + 255) / 256, 256, 0, stream>>>(Wl, Wr, Wc);
    count_edges<<<(E + 255) / 256, 256, 0, stream>>>(e_mt + E, cnt_t, E);
    count_edges<<<(E + 255) / 256, 256, 0, stream>>>(e_tm + E, cnt_m, E);
    make_inv<<<(Mt + 255) / 256, 256, 0, stream>>>(cnt_t, inv_t, Mt);
    make_inv<<<(Mm + 255) / 256, 256, 0, stream>>>(cnt_m, inv_m, Mm);

    const float* cur_m = x_m;
    const float* cur_t = x_t;
    for (int layer = 0; layer < 3; ++layer) {
        float *nxt_m, *nxt_t;
        if (layer == 1) { nxt_m = xm2;   nxt_t = xt2;   }
        else            { nxt_m = out_m; nxt_t = out_t; }
        const float* biasT = bl + ((size_t)layer * 2 + 0) * DIM;
        const float* biasM = bl + ((size_t)layer * 2 + 1) * DIM;
        const bf16_t* WcT = Wc + ((size_t)layer * 2 + 0) * 128 * 256;
        const bf16_t* WcM = Wc + ((size_t)layer * 2 + 1) * 128 * 256;

        // edge type 0: musician -> track (dst = track)
        hipMemsetAsync(agg, 0, (size_t)Mt * DIM * 4, stream);
        scatter_mean<<<(E + 3) / 4, 256, 0, stream>>>(cur_m, e_mt, e_mt + E, inv_t, agg, E);
        if (layer < 2)
            gemm_fused<true ><<<(Mt + 63) / 64, 256, 0, stream>>>(agg, cur_t, WcT, biasT, nxt_t, Mt);
        else
            gemm_fused<false><<<(Mt + 63) / 64, 256, 0, stream>>>(agg, cur_t, WcT, biasT, nxt_t, Mt);

        // edge type 1: track -> musician (dst = musician)
        hipMemsetAsync(agg, 0, (size_t)Mm * DIM * 4, stream);
        scatter_mean<<<(E + 3) / 4, 256, 0, stream>>>(cur_t, e_tm, e_tm + E, inv_m, agg, E);
        if (layer < 2)
            gemm_fused<true ><<<(Mm + 63) / 64, 256, 0, stream>>>(agg, cur_m, WcM, biasM, nxt_m, Mm);
        else
            gemm_fused<false><<<(Mm + 63) / 64, 256, 0, stream>>>(agg, cur_m, WcM, biasM, nxt_m, Mm);

        cur_m = nxt_m;
        cur_t = nxt_t;
    }
}

// Round 2
// 952.592 us; speedup vs baseline: 2.7757x; 2.7757x over previous
//
#include <hip/hip_runtime.h>
#include <hip/hip_bf16.h>

typedef __bf16 bf16_t;
typedef __attribute__((ext_vector_type(8))) __bf16 bf16x8;
typedef __attribute__((ext_vector_type(4))) float f32x4;

#define DIM 128

// ---------------- weight prep: Wc[s][n][k256] bf16, s = layer*2 + type ----------
__global__ void prep_weights(const float* __restrict__ Wl, const float* __restrict__ Wr,
                             bf16_t* __restrict__ Wc) {
    int idx = blockIdx.x * blockDim.x + threadIdx.x;   // over 6*128*256
    if (idx >= 6 * 128 * 256) return;
    int k = idx & 255;
    int n = (idx >> 8) & 127;
    int s = idx >> 15;                                  // 0..5
    float v;
    if (k < 128) v = Wl[((size_t)s * 128 + n) * 128 + k];
    else         v = Wr[((size_t)s * 128 + n) * 128 + (k - 128)];
    Wc[idx] = (bf16_t)v;
}

// ---------------- degree count + inverse ----------------
__global__ void count_edges(const int* __restrict__ dst, int* __restrict__ cnt, int E) {
    int i = blockIdx.x * blockDim.x + threadIdx.x;
    if (i < E) atomicAdd(&cnt[dst[i]], 1);
}

__global__ void make_inv(const int* __restrict__ cnt, float* __restrict__ inv, int n) {
    int i = blockIdx.x * blockDim.x + threadIdx.x;
    if (i < n) inv[i] = 1.0f / (float)max(cnt[i], 1);
}

// ---------------- CSR build: block scan ----------------
__global__ __launch_bounds__(256) void scan_local(const int* __restrict__ cnt,
                                                  int* __restrict__ partial,
                                                  int* __restrict__ blocksum, int M) {
    __shared__ int sdata[256];
    int i = blockIdx.x * 256 + threadIdx.x;
    int v = (i < M) ? cnt[i] : 0;
    sdata[threadIdx.x] = v;
    __syncthreads();
    for (int off = 1; off < 256; off <<= 1) {
        int t = (threadIdx.x >= off) ? sdata[threadIdx.x - off] : 0;
        __syncthreads();
        sdata[threadIdx.x] += t;
        __syncthreads();
    }
    int incl = sdata[threadIdx.x];
    if (i < M) partial[i] = incl - v;                 // exclusive within block
    if (threadIdx.x == 255) blocksum[blockIdx.x] = incl;
}

__global__ __launch_bounds__(256) void scan_blocks(int* __restrict__ blocksum, int NB) {
    __shared__ int sdata[256];
    __shared__ int running;
    if (threadIdx.x == 0) running = 0;
    __syncthreads();
    for (int base = 0; base < NB; base += 256) {
        int i = base + threadIdx.x;
        int v = (i < NB) ? blocksum[i] : 0;
        sdata[threadIdx.x] = v;
        __syncthreads();
        for (int off = 1; off < 256; off <<= 1) {
            int t = (threadIdx.x >= off) ? sdata[threadIdx.x - off] : 0;
            __syncthreads();
            sdata[threadIdx.x] += t;
            __syncthreads();
        }
        int incl = sdata[threadIdx.x];
        int r = running;
        __syncthreads();
        if (i < NB) blocksum[i] = incl - v + r;       // exclusive + chunk offset
        if (threadIdx.x == 0) running = r + sdata[255];
        __syncthreads();
    }
}

__global__ void add_offsets(const int* __restrict__ partial, const int* __restrict__ blocksum,
                            int* __restrict__ rowstart, int* __restrict__ cursor, int M) {
    int i = blockIdx.x * blockDim.x + threadIdx.x;
    if (i < M) {
        int rs = partial[i] + blocksum[i >> 8];
        rowstart[i] = rs;
        cursor[i] = rs;
    }
}

__global__ void bin_edges(const int* __restrict__ src, const int* __restrict__ dst,
                          int* __restrict__ cursor, int* __restrict__ csr_src, int E) {
    int e = blockIdx.x * blockDim.x + threadIdx.x;
    if (e < E) {
        int d = dst[e];
        int pos = atomicAdd(&cursor[d], 1);
        csr_src[pos] = src[e];
    }
}

// ---------------- gather-mean: one wave per dst row, no atomics ----------------
__global__ __launch_bounds__(256) void gather_mean(
    const float* __restrict__ xsrc, const int* __restrict__ rowstart,
    const int* __restrict__ cnt, const int* __restrict__ csr_src,
    float* __restrict__ agg, int M) {
    int d = blockIdx.x * 4 + (threadIdx.x >> 6);
    if (d >= M) return;
    int lane = threadIdx.x & 63;
    int start = rowstart[d];
    int n = cnt[d];
    float2 acc0 = {0.f, 0.f}, acc1 = {0.f, 0.f};
    int k = 0;
    for (; k + 1 < n; k += 2) {
        int s0 = csr_src[start + k];
        int s1 = csr_src[start + k + 1];
        float2 v0 = ((const float2*)(xsrc + (size_t)s0 * DIM))[lane];
        float2 v1 = ((const float2*)(xsrc + (size_t)s1 * DIM))[lane];
        acc0.x += v0.x; acc0.y += v0.y;
        acc1.x += v1.x; acc1.y += v1.y;
    }
    if (k < n) {
        int s = csr_src[start + k];
        float2 v = ((const float2*)(xsrc + (size_t)s * DIM))[lane];
        acc0.x += v.x; acc0.y += v.y;
    }
    float invn = 1.0f / (float)max(n, 1);
    float2 r;
    r.x = (acc0.x + acc1.x) * invn;
    r.y = (acc0.y + acc1.y) * invn;
    ((float2*)(agg + (size_t)d * DIM))[lane] = r;
}

// ---------------- fused GEMM: out = A0@Wl.T + bias + A1@Wr.T (+ReLU) ------------
template <bool RELU>
__global__ __launch_bounds__(256) void gemm_fused(
    const float* __restrict__ A0, const float* __restrict__ A1,
    const bf16_t* __restrict__ Wc, const float* __restrict__ bias,
    float* __restrict__ out, int M) {
    int wave = threadIdx.x >> 6;
    int lane = threadIdx.x & 63;
    int quad = lane >> 4;
    int l16  = lane & 15;
    int rowBase = blockIdx.x * 64 + wave * 16;
    int mrow = rowBase + l16;
    if (mrow >= M) mrow = M - 1;

    f32x4 acc[8];
#pragma unroll
    for (int ct = 0; ct < 8; ++ct) acc[ct] = (f32x4){0.f, 0.f, 0.f, 0.f};

#pragma unroll
    for (int kt = 0; kt < 8; ++kt) {
        const float* srcp = (kt < 4)
            ? (A0 + (size_t)mrow * DIM + kt * 32)
            : (A1 + (size_t)mrow * DIM + (kt - 4) * 32);
        const float4* p = (const float4*)(srcp + quad * 8);
        float4 a0 = p[0];
        float4 a1 = p[1];
        bf16x8 af;
        af[0] = (bf16_t)a0.x; af[1] = (bf16_t)a0.y;
        af[2] = (bf16_t)a0.z; af[3] = (bf16_t)a0.w;
        af[4] = (bf16_t)a1.x; af[5] = (bf16_t)a1.y;
        af[6] = (bf16_t)a1.z; af[7] = (bf16_t)a1.w;
#pragma unroll
        for (int ct = 0; ct < 8; ++ct) {
            const bf16x8* bp =
                (const bf16x8*)(Wc + ((size_t)(ct * 16 + l16)) * 256 + kt * 32 + quad * 8);
            bf16x8 bf = *bp;
            acc[ct] = __builtin_amdgcn_mfma_f32_16x16x32_bf16(af, bf, acc[ct], 0, 0, 0);
        }
    }

#pragma unroll
    for (int ct = 0; ct < 8; ++ct) {
        int col = ct * 16 + l16;
        float b = bias[col];
#pragma unroll
        for (int r = 0; r < 4; ++r) {
            int row = rowBase + quad * 4 + r;
            if (row < M) {
                float v = acc[ct][r] + b;
                if (RELU) v = fmaxf(v, 0.f);
                out[(size_t)row * DIM + col] = v;
            }
        }
    }
}

// ---------------- launch ----------------
extern "C" void kernel_launch(void* const* d_in, const int* in_sizes, int n_in,
                              void* d_out, int out_size, void* d_ws, size_t ws_size,
                              hipStream_t stream) {
    const float* x_m = (const float*)d_in[0];
    const float* x_t = (const float*)d_in[1];
    const float* Wl  = (const float*)d_in[2];
    const float* bl  = (const float*)d_in[3];
    const float* Wr  = (const float*)d_in[4];
    const int* e_mt  = (const int*)d_in[5];
    const int* e_tm  = (const int*)d_in[6];

    const int Mm = in_sizes[0] / DIM;     // 100000
    const int Mt = in_sizes[1] / DIM;     // 100000
    const int E  = in_sizes[5] / 2;       // 400000
    const int NBt = (Mt + 255) / 256;
    const int NBm = (Mm + 255) / 256;

    float* out_m = (float*)d_out;
    float* out_t = (float*)d_out + (size_t)Mm * DIM;

    char* ws = (char*)d_ws;
    size_t off = 0;
    auto alloc = [&](size_t bytes) -> void* {
        void* p = ws + off;
        off += (bytes + 255) & ~(size_t)255;
        return p;
    };
    float*  xm2    = (float*)alloc((size_t)Mm * DIM * 4);
    float*  xt2    = (float*)alloc((size_t)Mt * DIM * 4);
    float*  agg    = (float*)alloc((size_t)((Mm > Mt) ? Mm : Mt) * DIM * 4);
    float*  inv_t  = (float*)alloc((size_t)Mt * 4);
    float*  inv_m  = (float*)alloc((size_t)Mm * 4);
    int*    cnt_t  = (int*)alloc((size_t)Mt * 4);
    int*    cnt_m  = (int*)alloc((size_t)Mm * 4);
    int*    rs_t   = (int*)alloc((size_t)Mt * 4);
    int*    rs_m   = (int*)alloc((size_t)Mm * 4);
    int*    cur_tb = (int*)alloc((size_t)Mt * 4);
    int*    cur_mb = (int*)alloc((size_t)Mm * 4);
    int*    partial= (int*)alloc((size_t)((Mm > Mt) ? Mm : Mt) * 4);
    int*    bsum   = (int*)alloc((size_t)((NBt > NBm) ? NBt : NBm) * 4);
    int*    csr_t  = (int*)alloc((size_t)E * 4);
    int*    csr_m  = (int*)alloc((size_t)E * 4);
    bf16_t* Wc     = (bf16_t*)alloc((size_t)6 * 128 * 256 * 2);

    // ---- per-launch structure prep (graph-replayed every call) ----
    hipMemsetAsync(cnt_t, 0, (size_t)Mt * 4, stream);
    hipMemsetAsync(cnt_m, 0, (size_t)Mm * 4, stream);
    prep_weights<<<(6 * 128 * 256 + 255) / 256, 256, 0, stream>>>(Wl, Wr, Wc);
    count_edges<<<(E + 255) / 256, 256, 0, stream>>>(e_mt + E, cnt_t, E);
    count_edges<<<(E + 255) / 256, 256, 0, stream>>>(e_tm + E, cnt_m, E);
    make_inv<<<(Mt + 255) / 256, 256, 0, stream>>>(cnt_t, inv_t, Mt);
    make_inv<<<(Mm + 255) / 256, 256, 0, stream>>>(cnt_m, inv_m, Mm);

    // CSR for edge_mt (dst = track)
    scan_local<<<NBt, 256, 0, stream>>>(cnt_t, partial, bsum, Mt);
    scan_blocks<<<1, 256, 0, stream>>>(bsum, NBt);
    add_offsets<<<NBt, 256, 0, stream>>>(partial, bsum, rs_t, cur_tb, Mt);
    bin_edges<<<(E + 255) / 256, 256, 0, stream>>>(e_mt, e_mt + E, cur_tb, csr_t, E);

    // CSR for edge_tm (dst = musician)
    scan_local<<<NBm, 256, 0, stream>>>(cnt_m, partial, bsum, Mm);
    scan_blocks<<<1, 256, 0, stream>>>(bsum, NBm);
    add_offsets<<<NBm, 256, 0, stream>>>(partial, bsum, rs_m, cur_mb, Mm);
    bin_edges<<<(E + 255) / 256, 256, 0, stream>>>(e_tm, e_tm + E, cur_mb, csr_m, E);

    const float* cm = x_m;
    const float* ct = x_t;
    for (int layer = 0; layer < 3; ++layer) {
        float *nxt_m, *nxt_t;
        if (layer == 1) { nxt_m = xm2;   nxt_t = xt2;   }
        else            { nxt_m = out_m; nxt_t = out_t; }
        const float* biasT = bl + ((size_t)layer * 2 + 0) * DIM;
        const float* biasM = bl + ((size_t)layer * 2 + 1) * DIM;
        const bf16_t* WcT = Wc + ((size_t)layer * 2 + 0) * 128 * 256;
        const bf16_t* WcM = Wc + ((size_t)layer * 2 + 1) * 128 * 256;

        // edge type 0: musician -> track (dst = track)
        gather_mean<<<(Mt + 3) / 4, 256, 0, stream>>>(cm, rs_t, cnt_t, csr_t, agg, Mt);
        if (layer < 2)
            gemm_fused<true ><<<(Mt + 63) / 64, 256, 0, stream>>>(agg, ct, WcT, biasT, nxt_t, Mt);
        else
            gemm_fused<false><<<(Mt + 63) / 64, 256, 0, stream>>>(agg, ct, WcT, biasT, nxt_t, Mt);

        // edge type 1: track -> musician (dst = musician)
        gather_mean<<<(Mm + 3) / 4, 256, 0, stream>>>(ct, rs_m, cnt_m, csr_m, agg, Mm);
        if (layer < 2)
            gemm_fused<true ><<<(Mm + 63) / 64, 256, 0, stream>>>(agg, cm, WcM, biasM, nxt_m, Mm);
        else
            gemm_fused<false><<<(Mm + 63) / 64, 256, 0, stream>>>(agg, cm, WcM, biasM, nxt_m, Mm);

        cm = nxt_m;
        ct = nxt_t;
    }
}